// Round 4
// baseline (92.529 us; speedup 1.0000x reference)
//
#include <hip/hip_runtime.h>
#include <math.h>

#define CI 64
#define CO 128
#define CX 69
#define LPIX 1024   // 32*32

// ws layout (floats):
//   [0 : 65536)       q_part[4][16][1024]
//   [65536 : +73728)  w_t[576][128]   (k=ci*9+tap major, co minor)
//   [.. : +5760)      sk_t[45][128]
#define QPART_OFF 0
#define WT_OFF    65536
#define SKT_OFF   (65536 + 73728)

// ---------------------------------------------------------------------------
// prep: transpose conv weights and shape kernels for aligned s_load_dwordx8
// ---------------------------------------------------------------------------
__launch_bounds__(256)
__global__ void prep(const float* __restrict__ cwg,
                     const float* __restrict__ skg,
                     float* __restrict__ ws) {
  int i = blockIdx.x * 256 + threadIdx.x;
  if (i < 128 * 576) {
    int co = i / 576, k = i - co * 576;      // k = ci*9+tap
    ws[WT_OFF + k * 128 + co] = cwg[i];
  } else if (i < 128 * 576 + 128 * 45) {
    int j = i - 128 * 576;
    int co = j / 45, t = j - co * 45;
    ws[SKT_OFF + t * 128 + co] = skg[j];
  }
}

// ---------------------------------------------------------------------------
// Kernel A: conv3x3 (zero-pad) + shape-distance + saf + q partial
// grid: 512 blocks = 16 b x 8 stripes(4 rows) x 4 co-quarters, 256 threads.
// Wave = 4 rows x 32 cols, 2 px/lane (adjacent cols) x 8 co.
// Per ci per lane: 6 float2 LDS reads (-> ds_read2_b64) + 144 v_fmac with
// SGPR weight operands from the transposed layout. Explicit fA/fB prefetch.
// ---------------------------------------------------------------------------
__launch_bounds__(256, 2)
__global__ void convA(const float* __restrict__ xg,
                      const float* __restrict__ cbg,
                      const float* __restrict__ w2g,
                      float* __restrict__ ws,
                      float* __restrict__ outg) {
  __shared__ float lds_x[64 * 216];   // [ci][6 rows r0-1..r0+4][36 slots], zero-pad
  __shared__ float lds_sx[5 * 216];   // [c][6 rows][36 slots], edge-clamped
  __shared__ float qred[4][128];

  const int tid = threadIdx.x;
  const int blk = blockIdx.x;
  const int coq    = blk & 3;
  const int stripe = (blk >> 2) & 7;
  const int b      = blk >> 5;
  const int r0 = stripe * 4;

  const float* xb = xg + (size_t)b * CX * LPIX;
  const float* xs = xb + CI * LPIX;

  // stage conv input rows (zero padding), col slot j holds col j-1
  for (int idx = tid; idx < 64 * 216; idx += 256) {
    int ci = idx / 216, rem = idx - ci * 216;
    int s = rem / 36, j = rem - s * 36;
    int hh = r0 - 1 + s, col = j - 1;
    float v = 0.f;
    if ((unsigned)hh < 32u && (unsigned)col < 32u)
      v = xb[ci * LPIX + hh * 32 + col];
    lds_x[idx] = v;
  }
  // stage shape rows (edge clamp)
  for (int idx = tid; idx < 5 * 216; idx += 256) {
    int c = idx / 216, rem = idx - c * 216;
    int s = rem / 36, j = rem - s * 36;
    int hh = r0 - 1 + s; hh = hh < 0 ? 0 : (hh > 31 ? 31 : hh);
    int col = j - 1;     col = col < 0 ? 0 : (col > 31 ? 31 : col);
    lds_sx[idx] = xs[c * LPIX + hh * 32 + col];
  }
  __syncthreads();

  const int wv   = __builtin_amdgcn_readfirstlane(tid >> 6);  // wave 0..3
  const int co0  = coq * 32 + wv * 8;
  const int lane = tid & 63;
  const int pr  = lane >> 4;        // row within stripe 0..3
  const int cg2 = (lane & 15) * 2;  // first col of lane's 2 px
  const int xoff = pr * 36 + cg2;   // + s*36 + ci*216

  float acc0[8], acc1[8];
  #pragma unroll
  for (int cc = 0; cc < 8; ++cc) { acc0[cc] = cbg[co0 + cc]; acc1[cc] = acc0[cc]; }

  const float* wt = ws + WT_OFF + co0;   // wave-uniform

  float fA[12], fB[12];
  auto LDX = [&](float* f, int ci) {
    #pragma unroll
    for (int s = 0; s < 3; ++s) {
      const float* p = &lds_x[ci * 216 + s * 36 + xoff];
      float2 u = *(const float2*)p;
      float2 v = *(const float2*)(p + 2);
      f[s * 4 + 0] = u.x; f[s * 4 + 1] = u.y;
      f[s * 4 + 2] = v.x; f[s * 4 + 3] = v.y;
    }
  };
  auto FMA = [&](const float* f, int ci) {
    const float* wp = wt + (size_t)ci * 1152;   // 9*128
    #pragma unroll
    for (int t = 0; t < 9; ++t) {
      const int s = t / 3, dc = t % 3;
      #pragma unroll
      for (int cc = 0; cc < 8; ++cc) {
        float w = wp[t * 128 + cc];
        acc0[cc] = fmaf(f[s * 4 + dc],     w, acc0[cc]);
        acc1[cc] = fmaf(f[s * 4 + dc + 1], w, acc1[cc]);
      }
    }
  };

  LDX(fA, 0);
  for (int ci = 0; ci < 62; ci += 2) {
    LDX(fB, ci + 1);
    FMA(fA, ci);
    LDX(fA, ci + 2);
    FMA(fB, ci + 1);
  }
  LDX(fB, 63);
  FMA(fA, 62);
  FMA(fB, 63);

  // centers (row r0+pr -> staged row pr+1; col c -> slot c+1)
  const float c0p0 = lds_sx[36 + xoff + 1];
  const float c0p1 = lds_sx[36 + xoff + 2];
  const float c1p0 = lds_sx[216 + 36 + xoff + 1];
  const float c1p1 = lds_sx[216 + 36 + xoff + 2];

  // sd: wide LDS reads + per-tap s_load_dwordx8 of sk_t, rest pure VALU
  float sd0[8], sd1[8];
  #pragma unroll
  for (int cc = 0; cc < 8; ++cc) { sd0[cc] = 0.f; sd1[cc] = 0.f; }
  const float* skt = ws + SKT_OFF + co0;  // wave-uniform
  #pragma unroll
  for (int c5 = 0; c5 < 5; ++c5) {
    const float ca = (c5 == 0) ? c0p0 : ((c5 == 1) ? c1p0 : 0.f);
    const float cb = (c5 == 0) ? c0p1 : ((c5 == 1) ? c1p1 : 0.f);
    #pragma unroll
    for (int s = 0; s < 3; ++s) {
      const float* p = &lds_sx[c5 * 216 + s * 36 + xoff];
      float2 u = *(const float2*)p;
      float2 v = *(const float2*)(p + 2);
      float g[4] = {u.x, u.y, v.x, v.y};
      #pragma unroll
      for (int dc = 0; dc < 3; ++dc) {
        float a0 = g[dc] - ca;
        float a1 = g[dc + 1] - cb;
        const float* kp = skt + (c5 * 9 + s * 3 + dc) * 128;
        #pragma unroll
        for (int cc = 0; cc < 8; ++cc) {
          float k = kp[cc];
          sd0[cc] += fabsf(a0 - k);
          sd1[cc] += fabsf(a1 - k);
        }
      }
    }
  }

  // saf = relu(conv/(sd+1)); float2 store; q partials
  float qp0 = 0.f, qp1 = 0.f;
  float* outb = outg + ((size_t)b * 133 + co0) * LPIX + (r0 + pr) * 32 + cg2;
  #pragma unroll
  for (int cc = 0; cc < 8; ++cc) {
    float w2c = w2g[co0 + cc];
    float v0 = acc0[cc] * __builtin_amdgcn_rcpf(sd0[cc] + 1.0f);
    float v1 = acc1[cc] * __builtin_amdgcn_rcpf(sd1[cc] + 1.0f);
    v0 = v0 > 0.f ? v0 : 0.f;
    v1 = v1 > 0.f ? v1 : 0.f;
    *(float2*)(outb + (size_t)cc * LPIX) = make_float2(v0, v1);
    qp0 = fmaf(v0, w2c, qp0);
    qp1 = fmaf(v1, w2c, qp1);
  }

  // cross-wave q reduction (4 waves cover the 32 co of this quarter)
  *(float2*)&qred[wv][pr * 32 + cg2] = make_float2(qp0, qp1);
  __syncthreads();
  if (tid < 128) {
    float q = qred[0][tid] + qred[1][tid] + qred[2][tid] + qred[3][tid];
    ws[QPART_OFF + coq * 16384 + b * LPIX + r0 * 32 + tid] = q;
  }
}

// ---------------------------------------------------------------------------
// Kernel B: combine q quarters, 3x3 zero-padded softmax + weighted stats
// ---------------------------------------------------------------------------
__launch_bounds__(64)
__global__ void statsB(const float* __restrict__ xg,
                       const float* __restrict__ ws,
                       const float* __restrict__ b2g,
                       float* __restrict__ outg) {
  const int gid = blockIdx.x * 64 + threadIdx.x;  // 0..16383
  const int b = gid >> 10;
  const int h = (gid >> 5) & 31;
  const int w = gid & 31;

  const float b2 = b2g[0];
  const float* q0 = ws + QPART_OFF + (size_t)b * LPIX;
  float qv[9];
  float m = -1e30f;
  #pragma unroll
  for (int t = 0; t < 9; ++t) {
    int hh = h + t / 3 - 1, wc = w + t % 3 - 1;
    float v = 0.f;  // zero padding participates in softmax
    if ((unsigned)hh < 32u && (unsigned)wc < 32u) {
      int off = hh * 32 + wc;
      v = (q0[off] + q0[16384 + off] + q0[32768 + off] + q0[49152 + off] + b2)
          * 0.08838834764831845f;  // 1/sqrt(128)
    }
    qv[t] = v;
    m = fmaxf(m, v);
  }
  float ssum = 0.f;
  #pragma unroll
  for (int t = 0; t < 9; ++t) { qv[t] = expf(qv[t] - m); ssum += qv[t]; }
  const float inv = 1.f / ssum;

  const float* xs = xg + ((size_t)b * CX + CI) * LPIX;
  float um0[9], um1[9];
  float m0 = 0.f, m1 = 0.f, v1a = 0.f, v1b = 0.f, c1 = 0.f;
  #pragma unroll
  for (int t = 0; t < 9; ++t) {
    int hh = h + t / 3 - 1; hh = hh < 0 ? 0 : (hh > 31 ? 31 : hh);  // edge pad
    int wc = w + t % 3 - 1; wc = wc < 0 ? 0 : (wc > 31 ? 31 : wc);
    int off = hh * 32 + wc;
    float quv = qv[t] * inv;
    qv[t] = quv;
    float a0 = xs[off];
    float a1 = xs[LPIX + off];
    float b0 = xs[2 * LPIX + off];
    float b1 = xs[3 * LPIX + off];
    float cc = xs[4 * LPIX + off];
    um0[t] = a0; um1[t] = a1;
    m0 = fmaf(a0, quv, m0);
    m1 = fmaf(a1, quv, m1);
    v1a = fmaf(b0, quv, v1a);
    v1b = fmaf(b1, quv, v1b);
    c1 = fmaf(cc, quv, c1);
  }
  float var0 = v1a, var1 = v1b, cov = c1;
  #pragma unroll
  for (int t = 0; t < 9; ++t) {
    float d0 = um0[t] - m0, d1 = um1[t] - m1;
    var0 = fmaf(d0 * d0, qv[t], var0);
    var1 = fmaf(d1 * d1, qv[t], var1);
    cov  = fmaf(d0 * d1, qv[t], cov);
  }
  float* ob = outg + ((size_t)b * 133 + 128) * LPIX + h * 32 + w;
  ob[0 * LPIX] = m0;
  ob[1 * LPIX] = m1;
  ob[2 * LPIX] = var0;
  ob[3 * LPIX] = var1;
  ob[4 * LPIX] = cov;
}

extern "C" void kernel_launch(void* const* d_in, const int* in_sizes, int n_in,
                              void* d_out, int out_size, void* d_ws, size_t ws_size,
                              hipStream_t stream) {
  const float* x  = (const float*)d_in[0];
  const float* cw = (const float*)d_in[1];
  const float* cb = (const float*)d_in[2];
  const float* w2 = (const float*)d_in[3];
  const float* b2 = (const float*)d_in[4];
  const float* sk = (const float*)d_in[5];
  float* out = (float*)d_out;
  float* ws  = (float*)d_ws;   // needs (65536+73728+5760)*4 = ~580 KB

  prep<<<dim3(311), dim3(256), 0, stream>>>(cw, sk, ws);
  convA<<<dim3(512), dim3(256), 0, stream>>>(x, cb, w2, ws, out);
  statsB<<<dim3(256), dim3(64), 0, stream>>>(x, ws, b2, out);
}

// Round 5
// 43.331 us; speedup vs baseline: 2.1354x; 2.1354x over previous
//
#include <hip/hip_runtime.h>
#include <math.h>

#define CI 64
#define CO 128
#define CX 69
#define LPIX 1024   // 32*32

typedef __attribute__((ext_vector_type(8))) short bf16x8;
typedef __attribute__((ext_vector_type(4))) float f32x4;

// ws byte offsets
#define XT_OFF   0                        // u16[16*1024*64]  = 2 MB
#define WMF_OFF  (2*1024*1024)            // u16[9*128*64]    = 147456 B
#define SKT_OFF  (WMF_OFF + 147456)       // f32[45*128]      = 23040 B
#define QP_OFF   (SKT_OFF + 23040)       // f32[2*16*1024]    = 131072 B

__device__ __forceinline__ unsigned short f2bf(float f) {
  unsigned u = __float_as_uint(f);
  unsigned r = (u + 0x7fffu + ((u >> 16) & 1u)) >> 16;
  return (unsigned short)r;
}

// ---------------------------------------------------------------------------
// prepW: weights -> wmf[tap][co][ci ^ ((co&7)<<3)] bf16 (pre-swizzled so the
// LDS image is linear and frag ds_read_b128 is conflict-free);
// shapes_kernel -> skt[j][co] f32 for fuseC scalar loads.
// ---------------------------------------------------------------------------
__launch_bounds__(256)
__global__ void prepW(const float* __restrict__ cwg,
                      const float* __restrict__ skg,
                      unsigned short* __restrict__ wmf,
                      float* __restrict__ skt) {
  int i = blockIdx.x * 256 + threadIdx.x;
  if (i < 9 * 128 * 64) {
    int tap = i >> 13;
    int rem = i & 8191;
    int co = rem >> 6, cis = rem & 63;
    int ci = cis ^ ((co & 7) << 3);
    wmf[i] = f2bf(cwg[co * 576 + ci * 9 + tap]);
  } else {
    int d = i - 9 * 128 * 64;
    if (d < 45 * 128) {
      int j = d >> 7, co = d & 127;
      skt[j * 128 + co] = skg[co * 45 + j];
    }
  }
}

// ---------------------------------------------------------------------------
// prepX: transpose x[b][ci][px] f32 -> xT[b][px][ci] bf16 (LDS-tiled)
// grid 256 = 16 b x 16 px-chunks of 64, 256 threads
// ---------------------------------------------------------------------------
__launch_bounds__(256)
__global__ void prepX(const float* __restrict__ xg,
                      unsigned short* __restrict__ xT) {
  __shared__ float t[64][65];
  const int b  = blockIdx.x >> 4;
  const int p0 = (blockIdx.x & 15) * 64;
  const float* xb = xg + (size_t)b * CX * LPIX;
  const int tid = threadIdx.x;
  #pragma unroll
  for (int k = 0; k < 16; ++k) {
    int idx = tid + k * 256;
    int ci = idx >> 6, pxl = idx & 63;
    t[ci][pxl] = xb[ci * LPIX + p0 + pxl];
  }
  __syncthreads();
  const int pxl = tid >> 2, ci0 = (tid & 3) * 16;
  unsigned int pk[8];
  #pragma unroll
  for (int i = 0; i < 8; ++i) {
    unsigned short lo = f2bf(t[ci0 + 2 * i][pxl]);
    unsigned short hi = f2bf(t[ci0 + 2 * i + 1][pxl]);
    pk[i] = (unsigned)lo | ((unsigned)hi << 16);
  }
  uint4* dst = (uint4*)(xT + ((size_t)b * 1024 + p0 + pxl) * 64 + ci0);
  dst[0] = make_uint4(pk[0], pk[1], pk[2], pk[3]);
  dst[1] = make_uint4(pk[4], pk[5], pk[6], pk[7]);
}

// ---------------------------------------------------------------------------
// convMFMA: conv3x3 zero-pad as 9-tap implicit GEMM, bf16 MFMA 16x16x32.
// grid 256 = 16 b x 16 row-pairs; 256 thr = 4 waves.
// Wave w: px-row (r0 + (w>>1)), co-half (w&1): 2 px-tiles x 4 co-tiles.
// A (weights) from double-buffered LDS (lgkmcnt), B (x) direct global from
// xT (vmcnt) -> independent counters, no drain coupling.
// Writes RAW conv (no bias) to d_out channels 0..127; fuseC finishes.
// ---------------------------------------------------------------------------
__launch_bounds__(256)
__global__ void convMFMA(const unsigned short* __restrict__ xT,
                         const unsigned short* __restrict__ wmf,
                         float* __restrict__ outg) {
  __shared__ unsigned short ldsA[2][8192];   // 16 KB per tap buffer

  const int tid = threadIdx.x;
  const int b  = blockIdx.x >> 4;
  const int r0 = (blockIdx.x & 15) * 2;

  const int w    = tid >> 6;
  const int lane = tid & 63;
  const int coh  = w & 1;          // co half (0..1)
  const int prow = r0 + (w >> 1);  // this wave's output row
  const int n16  = lane & 15;
  const int kq   = lane >> 4;

  // stage tap 0 into buffer 0
  {
    const uint4* s = (const uint4*)wmf;
    uint4 v0 = s[tid], v1 = s[tid + 256], v2 = s[tid + 512], v3 = s[tid + 768];
    uint4* d = (uint4*)ldsA[0];
    d[tid] = v0; d[tid + 256] = v1; d[tid + 512] = v2; d[tid + 768] = v3;
  }
  __syncthreads();

  f32x4 acc[2][4] = {};
  const unsigned short* xTb = xT + (size_t)b * 65536;
  const bf16x8 bzero = {};

  for (int tap = 0; tap < 9; ++tap) {
    const int dr = tap / 3, dc = tap % 3;
    uint4 pf0, pf1, pf2, pf3;
    if (tap < 8) {
      const uint4* s = (const uint4*)(wmf + (tap + 1) * 8192);
      pf0 = s[tid]; pf1 = s[tid + 256]; pf2 = s[tid + 512]; pf3 = s[tid + 768];
    }
    const int row_g = prow + dr - 1;
    if ((unsigned)row_g < 32u) {
      const int c0 = n16 + dc - 1;        // tile col0 = 0
      const int c1 = 16 + n16 + dc - 1;   // tile col0 = 16
      const bool ok0 = (c0 >= 0);
      const bool ok1 = (c1 <= 31);
      const int c0c = ok0 ? c0 : 0;
      const int c1c = ok1 ? c1 : 31;
      const unsigned short* bp0 = xTb + (row_g * 32 + c0c) * 64;
      const unsigned short* bp1 = xTb + (row_g * 32 + c1c) * 64;
      const unsigned short* abase = ldsA[tap & 1];
      #pragma unroll
      for (int ci0 = 0; ci0 < 64; ci0 += 32) {
        const int cib = ci0 + kq * 8;
        bf16x8 b0 = *(const bf16x8*)(bp0 + cib);
        bf16x8 b1 = *(const bf16x8*)(bp1 + cib);
        if (!ok0) b0 = bzero;
        if (!ok1) b1 = bzero;
        const int gs = ((kq | (ci0 >> 3)) ^ (n16 & 7)) << 3;
        #pragma unroll
        for (int ct = 0; ct < 4; ++ct) {
          const int co_l = coh * 64 + ct * 16 + n16;
          bf16x8 a = *(const bf16x8*)(abase + co_l * 64 + gs);
          acc[0][ct] = __builtin_amdgcn_mfma_f32_16x16x32_bf16(a, b0, acc[0][ct], 0, 0, 0);
          acc[1][ct] = __builtin_amdgcn_mfma_f32_16x16x32_bf16(a, b1, acc[1][ct], 0, 0, 0);
        }
      }
    }
    if (tap < 8) {
      uint4* d = (uint4*)ldsA[(tap + 1) & 1];
      d[tid] = pf0; d[tid + 256] = pf1; d[tid + 512] = pf2; d[tid + 768] = pf3;
    }
    __syncthreads();
  }

  // C/D layout: col(px) = lane&15, row(co within tile) = kq*4 + reg
  float* ob = outg + (size_t)b * 133 * LPIX;
  #pragma unroll
  for (int pt = 0; pt < 2; ++pt) {
    const int px = prow * 32 + pt * 16 + n16;
    #pragma unroll
    for (int ct = 0; ct < 4; ++ct) {
      const int cobase = coh * 64 + ct * 16 + kq * 4;
      #pragma unroll
      for (int r = 0; r < 4; ++r)
        ob[(size_t)(cobase + r) * LPIX + px] = acc[pt][ct][r];
    }
  }
}

// ---------------------------------------------------------------------------
// fuseC: read raw conv from d_out, add bias, shape-distance, saf (in-place),
// q partial. grid 512 = 16b x 16 stripes(2 rows) x 2 co-halves, 512 thr.
// ---------------------------------------------------------------------------
__launch_bounds__(512, 4)
__global__ void fuseC(const float* __restrict__ xg,
                      const float* __restrict__ cbg,
                      const float* __restrict__ w2g,
                      const float* __restrict__ sktg,
                      float* __restrict__ qp,
                      float* __restrict__ outg) {
  __shared__ float lds_sx[5 * 144];   // [c][4 rows r0-1..r0+2][36 cols], edge-clamp
  __shared__ float qred[8][64];

  const int tid  = threadIdx.x;
  const int blk  = blockIdx.x;
  const int chf  = blk & 1;
  const int r0   = ((blk >> 1) & 15) * 2;
  const int b    = blk >> 5;

  const float* xs = xg + ((size_t)b * CX + CI) * LPIX;

  for (int idx = tid; idx < 5 * 144; idx += 512) {
    int c = idx / 144, rem = idx - c * 144;
    int s = rem / 36, j = rem - s * 36;
    int hh = r0 - 1 + s; hh = hh < 0 ? 0 : (hh > 31 ? 31 : hh);
    int col = j - 1;     col = col < 0 ? 0 : (col > 31 ? 31 : col);
    lds_sx[idx] = xs[c * LPIX + hh * 32 + col];
  }
  __syncthreads();

  const int wv   = __builtin_amdgcn_readfirstlane(tid >> 6);
  const int co0  = chf * 64 + wv * 8;
  const int lane = tid & 63;
  const int pr = lane >> 5, wc = lane & 31;
  const int xbase = pr * 36 + wc;

  // read raw conv + bias
  float acc[8];
  float* cvb = outg + ((size_t)b * 133 + co0) * LPIX + (r0 + pr) * 32 + wc;
  #pragma unroll
  for (int cc = 0; cc < 8; ++cc) acc[cc] = cvb[(size_t)cc * LPIX] + cbg[co0 + cc];

  // shape windows into registers (center-relative for channels 0,1)
  float swv[45];
  {
    const float c0 = lds_sx[0 * 144 + 37 + xbase];
    const float c1 = lds_sx[1 * 144 + 37 + xbase];
    #pragma unroll
    for (int c = 0; c < 5; ++c) {
      float ctr = (c == 0) ? c0 : ((c == 1) ? c1 : 0.f);
      #pragma unroll
      for (int s = 0; s < 3; ++s)
        #pragma unroll
        for (int dc = 0; dc < 3; ++dc)
          swv[c * 9 + s * 3 + dc] = lds_sx[c * 144 + s * 36 + dc + xbase] - ctr;
    }
  }

  // sd via scalar loads of skt (wave-uniform) + pure VALU
  float sdv[8];
  #pragma unroll
  for (int cc = 0; cc < 8; ++cc) sdv[cc] = 0.f;
  const float* skt = sktg + co0;
  #pragma unroll
  for (int j = 0; j < 45; ++j) {
    float sv = swv[j];
    #pragma unroll
    for (int cc = 0; cc < 8; ++cc)
      sdv[cc] += fabsf(sv - skt[j * 128 + cc]);
  }

  // saf = relu(conv/(sd+1)); overwrite in place; q partial
  float qpv = 0.f;
  #pragma unroll
  for (int cc = 0; cc < 8; ++cc) {
    float v = acc[cc] * __builtin_amdgcn_rcpf(sdv[cc] + 1.0f);
    v = v > 0.f ? v : 0.f;
    cvb[(size_t)cc * LPIX] = v;
    qpv = fmaf(v, w2g[co0 + cc], qpv);
  }

  qred[wv][lane] = qpv;
  __syncthreads();
  if (tid < 64) {
    float q = 0.f;
    #pragma unroll
    for (int w8 = 0; w8 < 8; ++w8) q += qred[w8][tid];
    qp[chf * 16384 + b * LPIX + (r0 + (tid >> 5)) * 32 + (tid & 31)] = q;
  }
}

// ---------------------------------------------------------------------------
// statsB: combine q halves, 3x3 zero-padded softmax + weighted window stats
// ---------------------------------------------------------------------------
__launch_bounds__(64)
__global__ void statsB(const float* __restrict__ xg,
                       const float* __restrict__ qp,
                       const float* __restrict__ b2g,
                       float* __restrict__ outg) {
  const int gid = blockIdx.x * 64 + threadIdx.x;  // 0..16383
  const int b = gid >> 10;
  const int h = (gid >> 5) & 31;
  const int w = gid & 31;

  const float b2 = b2g[0];
  const float* q0 = qp + (size_t)b * LPIX;
  float qv[9];
  float m = -1e30f;
  #pragma unroll
  for (int t = 0; t < 9; ++t) {
    int hh = h + t / 3 - 1, wc = w + t % 3 - 1;
    float v = 0.f;  // zero padding participates in softmax
    if ((unsigned)hh < 32u && (unsigned)wc < 32u) {
      int off = hh * 32 + wc;
      v = (q0[off] + q0[16384 + off] + b2) * 0.08838834764831845f;  // 1/sqrt(128)
    }
    qv[t] = v;
    m = fmaxf(m, v);
  }
  float ssum = 0.f;
  #pragma unroll
  for (int t = 0; t < 9; ++t) { qv[t] = expf(qv[t] - m); ssum += qv[t]; }
  const float inv = 1.f / ssum;

  const float* xs = xg + ((size_t)b * CX + CI) * LPIX;
  float um0[9], um1[9];
  float m0 = 0.f, m1 = 0.f, v1a = 0.f, v1b = 0.f, c1 = 0.f;
  #pragma unroll
  for (int t = 0; t < 9; ++t) {
    int hh = h + t / 3 - 1; hh = hh < 0 ? 0 : (hh > 31 ? 31 : hh);  // edge pad
    int wc = w + t % 3 - 1; wc = wc < 0 ? 0 : (wc > 31 ? 31 : wc);
    int off = hh * 32 + wc;
    float quv = qv[t] * inv;
    qv[t] = quv;
    float a0 = xs[off];
    float a1 = xs[LPIX + off];
    float b0 = xs[2 * LPIX + off];
    float b1 = xs[3 * LPIX + off];
    float cc = xs[4 * LPIX + off];
    um0[t] = a0; um1[t] = a1;
    m0 = fmaf(a0, quv, m0);
    m1 = fmaf(a1, quv, m1);
    v1a = fmaf(b0, quv, v1a);
    v1b = fmaf(b1, quv, v1b);
    c1 = fmaf(cc, quv, c1);
  }
  float var0 = v1a, var1 = v1b, cov = c1;
  #pragma unroll
  for (int t = 0; t < 9; ++t) {
    float d0 = um0[t] - m0, d1 = um1[t] - m1;
    var0 = fmaf(d0 * d0, qv[t], var0);
    var1 = fmaf(d1 * d1, qv[t], var1);
    cov  = fmaf(d0 * d1, qv[t], cov);
  }
  float* ob = outg + ((size_t)b * 133 + 128) * LPIX + h * 32 + w;
  ob[0 * LPIX] = m0;
  ob[1 * LPIX] = m1;
  ob[2 * LPIX] = var0;
  ob[3 * LPIX] = var1;
  ob[4 * LPIX] = cov;
}

extern "C" void kernel_launch(void* const* d_in, const int* in_sizes, int n_in,
                              void* d_out, int out_size, void* d_ws, size_t ws_size,
                              hipStream_t stream) {
  const float* x  = (const float*)d_in[0];
  const float* cw = (const float*)d_in[1];
  const float* cb = (const float*)d_in[2];
  const float* w2 = (const float*)d_in[3];
  const float* b2 = (const float*)d_in[4];
  const float* sk = (const float*)d_in[5];
  float* out = (float*)d_out;

  unsigned short* xT  = (unsigned short*)((char*)d_ws + XT_OFF);
  unsigned short* wmf = (unsigned short*)((char*)d_ws + WMF_OFF);
  float* skt = (float*)((char*)d_ws + SKT_OFF);
  float* qp  = (float*)((char*)d_ws + QP_OFF);

  prepW<<<dim3(311), dim3(256), 0, stream>>>(cw, sk, wmf, skt);
  prepX<<<dim3(256), dim3(256), 0, stream>>>(x, xT);
  convMFMA<<<dim3(256), dim3(256), 0, stream>>>(xT, wmf, out);
  fuseC<<<dim3(512), dim3(512), 0, stream>>>(x, cb, w2, skt, qp, out);
  statsB<<<dim3(256), dim3(64), 0, stream>>>(x, qp, b2, out);
}

// Round 6
// 36.602 us; speedup vs baseline: 2.5280x; 1.1839x over previous
//
#include <hip/hip_runtime.h>
#include <math.h>

#define CI 64
#define CO 128
#define CX 69
#define LPIX 1024   // 32*32

typedef __attribute__((ext_vector_type(8))) short bf16x8;
typedef __attribute__((ext_vector_type(4))) float f32x4;

// ws byte offsets
#define XT_OFF   0                        // u16[16*1024*64]  = 2 MB
#define WMF_OFF  (2*1024*1024)            // u16[9*128*64]    = 147456 B
#define SKT_OFF  (WMF_OFF + 147456)       // f32[45*128]      = 23040 B
#define QP_OFF   (SKT_OFF + 23040)        // f32[2*16*1024]   = 131072 B

__device__ __forceinline__ unsigned short f2bf(float f) {
  unsigned u = __float_as_uint(f);
  unsigned r = (u + 0x7fffu + ((u >> 16) & 1u)) >> 16;
  return (unsigned short)r;
}

// ---------------------------------------------------------------------------
// prep (fused): blocks 0..255: transpose x[b][ci][px] f32 -> xT[b][px][ci] bf16.
// blocks 256..566: weights -> wmf[tap][co][ci ^ ((co&7)<<3)] bf16 (pre-swizzled
// so LDS A-image is linear + frag ds_read_b128 conflict-free), and
// shapes_kernel -> skt[j][co] f32.
// ---------------------------------------------------------------------------
__launch_bounds__(256)
__global__ void prep(const float* __restrict__ xg,
                     const float* __restrict__ cwg,
                     const float* __restrict__ skg,
                     unsigned short* __restrict__ xT,
                     unsigned short* __restrict__ wmf,
                     float* __restrict__ skt) {
  __shared__ float t[64][65];
  const int tid = threadIdx.x;
  if (blockIdx.x < 256) {
    const int b  = blockIdx.x >> 4;
    const int p0 = (blockIdx.x & 15) * 64;
    const float* xb = xg + (size_t)b * CX * LPIX;
    #pragma unroll
    for (int k = 0; k < 16; ++k) {
      int idx = tid + k * 256;
      int ci = idx >> 6, pxl = idx & 63;
      t[ci][pxl] = xb[ci * LPIX + p0 + pxl];
    }
    __syncthreads();
    const int pxl = tid >> 2, ci0 = (tid & 3) * 16;
    unsigned int pk[8];
    #pragma unroll
    for (int i = 0; i < 8; ++i) {
      unsigned short lo = f2bf(t[ci0 + 2 * i][pxl]);
      unsigned short hi = f2bf(t[ci0 + 2 * i + 1][pxl]);
      pk[i] = (unsigned)lo | ((unsigned)hi << 16);
    }
    uint4* dst = (uint4*)(xT + ((size_t)b * 1024 + p0 + pxl) * 64 + ci0);
    dst[0] = make_uint4(pk[0], pk[1], pk[2], pk[3]);
    dst[1] = make_uint4(pk[4], pk[5], pk[6], pk[7]);
  } else {
    int i = (blockIdx.x - 256) * 256 + tid;
    if (i < 9 * 128 * 64) {
      int tap = i >> 13;
      int rem = i & 8191;
      int co = rem >> 6, cis = rem & 63;
      int ci = cis ^ ((co & 7) << 3);
      wmf[i] = f2bf(cwg[co * 576 + ci * 9 + tap]);
    } else {
      int d = i - 9 * 128 * 64;
      if (d < 45 * 128) {
        int j = d >> 7, co = d & 127;
        skt[j * 128 + co] = skg[co * 45 + j];
      }
    }
  }
}

// ---------------------------------------------------------------------------
// convFused: conv3x3 (zero-pad) via bf16 MFMA 16x16x32 + fused epilogue
// (bias, L1 shape-distance, saf, q partial) in one kernel.
// grid 512 = 16 b x 16 row-pairs x 2 co-halves; 256 thr = 4 waves.
// MFMA phase: wave = (row, co-quarter of half): acc[2 px-tiles][2 co-tiles].
// A (weights, this half) double-buffered in LDS (lgkmcnt), B (x) direct
// global from xT (vmcnt) -> independent counters.
// Epilogue: acc transposed through LDS (aliases dead A buffers, XOR-swizzled
// [px][co] so b128 write/read hit the 8-cyc data floor), then wave = 16-co
// chunk, lane = pixel: sd via wave-uniform s_loads + pure VALU.
// ---------------------------------------------------------------------------
__launch_bounds__(256, 3)
__global__ void convFused(const unsigned short* __restrict__ xT,
                          const unsigned short* __restrict__ wmf,
                          const float* __restrict__ xg,
                          const float* __restrict__ cbg,
                          const float* __restrict__ w2g,
                          const float* __restrict__ sktg,
                          float* __restrict__ qp,
                          float* __restrict__ outg) {
  __shared__ char arena[16384];     // A dbuf (2 x 8 KB) -> later lds_c (16 KB)
  __shared__ float lds_sx[5 * 144]; // shape rows, edge-clamped
  __shared__ float qred[4][64];

  unsigned short* A0 = (unsigned short*)arena;
  float* lds_c = (float*)arena;

  const int tid = threadIdx.x;
  const int blk = blockIdx.x;
  const int coh = blk & 1;
  const int rp  = (blk >> 1) & 15;
  const int b   = blk >> 5;
  const int r0  = rp * 2;

  const int w    = tid >> 6;
  const int lane = tid & 63;
  const int rsel = w >> 1;          // MFMA-phase: wave's row within pair
  const int cq   = w & 1;           // MFMA-phase: co quarter within half
  const int prow = r0 + rsel;
  const int n16  = lane & 15;
  const int kq   = lane >> 4;

  // stage shape rows (edge clamp) for the epilogue
  const float* xs = xg + ((size_t)b * CX + CI) * LPIX;
  for (int idx = tid; idx < 5 * 144; idx += 256) {
    int c = idx / 144, rem = idx - c * 144;
    int s = rem / 36, j = rem - s * 36;
    int hh = r0 - 1 + s; hh = hh < 0 ? 0 : (hh > 31 ? 31 : hh);
    int col = j - 1;     col = col < 0 ? 0 : (col > 31 ? 31 : col);
    lds_sx[idx] = xs[c * LPIX + hh * 32 + col];
  }

  // stage tap 0 A-tile (this co half: 64 co x 64 ci bf16 = 8 KB)
  {
    const uint4* s = (const uint4*)(wmf + (size_t)(coh * 64) * 64);
    uint4 v0 = s[tid], v1 = s[tid + 256];
    uint4* d = (uint4*)A0;
    d[tid] = v0; d[tid + 256] = v1;
  }
  __syncthreads();

  f32x4 acc[2][2] = {};
  const unsigned short* xTb = xT + (size_t)b * 65536;
  const bf16x8 bzero = {};

  for (int tap = 0; tap < 9; ++tap) {
    const int dr = tap / 3, dc = tap % 3;
    uint4 pf0, pf1;
    if (tap < 8) {
      const uint4* s = (const uint4*)(wmf + (size_t)((tap + 1) * 128 + coh * 64) * 64);
      pf0 = s[tid]; pf1 = s[tid + 256];
    }
    const int row_g = prow + dr - 1;
    if ((unsigned)row_g < 32u) {
      const int c0 = n16 + dc - 1;
      const int c1 = 16 + n16 + dc - 1;
      const bool ok0 = (c0 >= 0);
      const bool ok1 = (c1 <= 31);
      const unsigned short* bp0 = xTb + (row_g * 32 + (ok0 ? c0 : 0)) * 64;
      const unsigned short* bp1 = xTb + (row_g * 32 + (ok1 ? c1 : 31)) * 64;
      const unsigned short* abase = A0 + (tap & 1) * 4096;
      #pragma unroll
      for (int ci0 = 0; ci0 < 64; ci0 += 32) {
        const int cib = ci0 + kq * 8;
        bf16x8 b0 = *(const bf16x8*)(bp0 + cib);
        bf16x8 b1 = *(const bf16x8*)(bp1 + cib);
        if (!ok0) b0 = bzero;
        if (!ok1) b1 = bzero;
        const int gs = ((kq | (ci0 >> 3)) ^ (n16 & 7)) << 3;
        #pragma unroll
        for (int ct = 0; ct < 2; ++ct) {
          const int co_l = cq * 32 + ct * 16 + n16;
          bf16x8 a = *(const bf16x8*)(abase + co_l * 64 + gs);
          acc[0][ct] = __builtin_amdgcn_mfma_f32_16x16x32_bf16(a, b0, acc[0][ct], 0, 0, 0);
          acc[1][ct] = __builtin_amdgcn_mfma_f32_16x16x32_bf16(a, b1, acc[1][ct], 0, 0, 0);
        }
      }
    }
    if (tap < 8) {
      uint4* d = (uint4*)(A0 + ((tap + 1) & 1) * 4096);
      d[tid] = pf0; d[tid + 256] = pf1;
    }
    __syncthreads();   // also separates last A-reads from lds_c writes below
  }

  // transpose acc through LDS: [px 0..63][co_l 0..63], XOR-swizzled float4 groups
  // C layout (validated r5): col(px in tile)=n16, row(co in tile)=kq*4+reg
  #pragma unroll
  for (int pt = 0; pt < 2; ++pt) {
    const int pxl = rsel * 32 + pt * 16 + n16;
    #pragma unroll
    for (int ct = 0; ct < 2; ++ct) {
      const int cog = cq * 8 + ct * 4 + kq;       // co_l/4 group: 0..15
      const int sg  = cog ^ (pxl & 7);
      *(f32x4*)&lds_c[pxl * 64 + sg * 4] = acc[pt][ct];
    }
  }
  __syncthreads();

  // ---- epilogue: wave wS -> co chunk [wS*16, wS*16+16) of this half; lane = px
  const int wS   = __builtin_amdgcn_readfirstlane(w);
  const int co0g = coh * 64 + wS * 16;
  const int pxl  = lane;

  float cvals[16];
  #pragma unroll
  for (int g = 0; g < 4; ++g) {
    const int cog = wS * 4 + g;
    const int sg  = cog ^ (pxl & 7);
    *(f32x4*)&cvals[g * 4] = *(const f32x4*)&lds_c[pxl * 64 + sg * 4];
  }

  // shape windows into registers (center-relative for channels 0,1)
  const int xbase = (pxl >> 5) * 36 + (pxl & 31);
  float swv[45];
  {
    const float c0 = lds_sx[0 * 144 + 37 + xbase];
    const float c1 = lds_sx[1 * 144 + 37 + xbase];
    #pragma unroll
    for (int c = 0; c < 5; ++c) {
      float ctr = (c == 0) ? c0 : ((c == 1) ? c1 : 0.f);
      #pragma unroll
      for (int s = 0; s < 3; ++s)
        #pragma unroll
        for (int dc = 0; dc < 3; ++dc)
          swv[c * 9 + s * 3 + dc] = lds_sx[c * 144 + s * 36 + dc + xbase] - ctr;
    }
  }

  // sd via wave-uniform scalar loads + pure VALU
  float sd[16];
  #pragma unroll
  for (int k = 0; k < 16; ++k) sd[k] = 0.f;
  const float* skt = sktg + co0g;
  #pragma unroll
  for (int j = 0; j < 45; ++j) {
    const float sv = swv[j];
    #pragma unroll
    for (int k = 0; k < 16; ++k)
      sd[k] += fabsf(sv - skt[j * 128 + k]);
  }

  // bias + saf = relu(conv/(sd+1)) + store + q partial
  float qpv = 0.f;
  float* ob = outg + ((size_t)b * 133 + co0g) * LPIX + (r0 + (pxl >> 5)) * 32 + (pxl & 31);
  #pragma unroll
  for (int k = 0; k < 16; ++k) {
    float v = (cvals[k] + cbg[co0g + k]) * __builtin_amdgcn_rcpf(sd[k] + 1.0f);
    v = v > 0.f ? v : 0.f;
    ob[(size_t)k * LPIX] = v;
    qpv = fmaf(v, w2g[co0g + k], qpv);
  }

  // in-block q reduction over the 4 waves (this half's 64 co)
  qred[w][lane] = qpv;
  __syncthreads();
  if (tid < 64) {
    float q = qred[0][tid] + qred[1][tid] + qred[2][tid] + qred[3][tid];
    qp[coh * 16384 + b * LPIX + r0 * 32 + tid] = q;
  }
}

// ---------------------------------------------------------------------------
// statsB: combine q halves, 3x3 zero-padded softmax + weighted window stats
// ---------------------------------------------------------------------------
__launch_bounds__(64)
__global__ void statsB(const float* __restrict__ xg,
                       const float* __restrict__ qp,
                       const float* __restrict__ b2g,
                       float* __restrict__ outg) {
  const int gid = blockIdx.x * 64 + threadIdx.x;  // 0..16383
  const int b = gid >> 10;
  const int h = (gid >> 5) & 31;
  const int w = gid & 31;

  const float b2 = b2g[0];
  const float* q0 = qp + (size_t)b * LPIX;
  float qv[9];
  float m = -1e30f;
  #pragma unroll
  for (int t = 0; t < 9; ++t) {
    int hh = h + t / 3 - 1, wc = w + t % 3 - 1;
    float v = 0.f;  // zero padding participates in softmax
    if ((unsigned)hh < 32u && (unsigned)wc < 32u) {
      int off = hh * 32 + wc;
      v = (q0[off] + q0[16384 + off] + b2) * 0.08838834764831845f;  // 1/sqrt(128)
    }
    qv[t] = v;
    m = fmaxf(m, v);
  }
  float ssum = 0.f;
  #pragma unroll
  for (int t = 0; t < 9; ++t) { qv[t] = expf(qv[t] - m); ssum += qv[t]; }
  const float inv = 1.f / ssum;

  const float* xs = xg + ((size_t)b * CX + CI) * LPIX;
  float um0[9], um1[9];
  float m0 = 0.f, m1 = 0.f, v1a = 0.f, v1b = 0.f, c1 = 0.f;
  #pragma unroll
  for (int t = 0; t < 9; ++t) {
    int hh = h + t / 3 - 1; hh = hh < 0 ? 0 : (hh > 31 ? 31 : hh);  // edge pad
    int wc = w + t % 3 - 1; wc = wc < 0 ? 0 : (wc > 31 ? 31 : wc);
    int off = hh * 32 + wc;
    float quv = qv[t] * inv;
    qv[t] = quv;
    float a0 = xs[off];
    float a1 = xs[LPIX + off];
    float b0 = xs[2 * LPIX + off];
    float b1 = xs[3 * LPIX + off];
    float cc = xs[4 * LPIX + off];
    um0[t] = a0; um1[t] = a1;
    m0 = fmaf(a0, quv, m0);
    m1 = fmaf(a1, quv, m1);
    v1a = fmaf(b0, quv, v1a);
    v1b = fmaf(b1, quv, v1b);
    c1 = fmaf(cc, quv, c1);
  }
  float var0 = v1a, var1 = v1b, cov = c1;
  #pragma unroll
  for (int t = 0; t < 9; ++t) {
    float d0 = um0[t] - m0, d1 = um1[t] - m1;
    var0 = fmaf(d0 * d0, qv[t], var0);
    var1 = fmaf(d1 * d1, qv[t], var1);
    cov  = fmaf(d0 * d1, qv[t], cov);
  }
  float* ob = outg + ((size_t)b * 133 + 128) * LPIX + h * 32 + w;
  ob[0 * LPIX] = m0;
  ob[1 * LPIX] = m1;
  ob[2 * LPIX] = var0;
  ob[3 * LPIX] = var1;
  ob[4 * LPIX] = cov;
}

extern "C" void kernel_launch(void* const* d_in, const int* in_sizes, int n_in,
                              void* d_out, int out_size, void* d_ws, size_t ws_size,
                              hipStream_t stream) {
  const float* x  = (const float*)d_in[0];
  const float* cw = (const float*)d_in[1];
  const float* cb = (const float*)d_in[2];
  const float* w2 = (const float*)d_in[3];
  const float* b2 = (const float*)d_in[4];
  const float* sk = (const float*)d_in[5];
  float* out = (float*)d_out;

  unsigned short* xT  = (unsigned short*)((char*)d_ws + XT_OFF);
  unsigned short* wmf = (unsigned short*)((char*)d_ws + WMF_OFF);
  float* skt = (float*)((char*)d_ws + SKT_OFF);
  float* qp  = (float*)((char*)d_ws + QP_OFF);

  prep<<<dim3(567), dim3(256), 0, stream>>>(x, cw, sk, xT, wmf, skt);
  convFused<<<dim3(512), dim3(256), 0, stream>>>(xT, wmf, x, cb, w2, skt, qp, out);
  statsB<<<dim3(256), dim3(64), 0, stream>>>(x, qp, b2, out);
}

// Round 7
// 32.179 us; speedup vs baseline: 2.8755x; 1.1374x over previous
//
#include <hip/hip_runtime.h>
#include <math.h>

#define CI 64
#define CO 128
#define CX 69
#define LPIX 1024   // 32*32

typedef __attribute__((ext_vector_type(8))) short bf16x8;
typedef __attribute__((ext_vector_type(4))) float f32x4;

// ws byte offsets
#define WMF_OFF  0                        // u16[9*128*64] = 147456 B
#define SKT_OFF  147456                   // f32[45*128]   = 23040 B
#define QP_OFF   (147456 + 23040)         // f32[2*16*1024]= 131072 B

__device__ __forceinline__ unsigned short f2bf(float f) {
  unsigned u = __float_as_uint(f);
  unsigned r = (u + 0x7fffu + ((u >> 16) & 1u)) >> 16;
  return (unsigned short)r;
}

// ---------------------------------------------------------------------------
// prepW: weights -> wmf[tap][co][ci ^ ((co&7)<<3)] bf16 (pre-swizzled so the
// LDS A-image is linear + frag ds_read_b128 conflict-free);
// shapes_kernel -> skt[j][co] f32. Tiny kernel (~170 KB of traffic).
// ---------------------------------------------------------------------------
__launch_bounds__(256)
__global__ void prepW(const float* __restrict__ cwg,
                      const float* __restrict__ skg,
                      unsigned short* __restrict__ wmf,
                      float* __restrict__ skt) {
  int i = blockIdx.x * 256 + threadIdx.x;
  if (i < 9 * 128 * 64) {
    int tap = i >> 13;
    int rem = i & 8191;
    int co = rem >> 6, cis = rem & 63;
    int ci = cis ^ ((co & 7) << 3);
    wmf[i] = f2bf(cwg[co * 576 + ci * 9 + tap]);
  } else {
    int d = i - 9 * 128 * 64;
    if (d < 45 * 128) {
      int j = d >> 7, co = d & 127;
      skt[j * 128 + co] = skg[co * 45 + j];
    }
  }
}

// ---------------------------------------------------------------------------
// convFused: conv3x3 (zero-pad) via bf16 MFMA 16x16x32 + fused epilogue
// (bias, L1 shape-distance, saf, q partial) in one kernel.
// grid 512 = 16 b x 16 row-pairs x 2 co-halves; 256 thr = 4 waves.
// B (x window) staged per block: [4 rows][36 col-slots][64 ci^swz] bf16 with
// zero-padded rows/cols -> uniform tap loop, no masks, conflict-free b128.
// A (weights, this half) double-buffered in LDS from pre-swizzled wmf.
// Epilogue: acc transposed through LDS (aliases dead A dbuf), wave = 16-co
// chunk, lane = pixel: sd via wave-uniform s_loads + pure VALU.
// ---------------------------------------------------------------------------
__launch_bounds__(256, 3)
__global__ void convFused(const float* __restrict__ xg,
                          const unsigned short* __restrict__ wmf,
                          const float* __restrict__ cbg,
                          const float* __restrict__ w2g,
                          const float* __restrict__ sktg,
                          float* __restrict__ qp,
                          float* __restrict__ outg) {
  __shared__ char arena[16384];              // A dbuf (2x8KB) -> lds_c (16KB)
  __shared__ unsigned short ldsB[4 * 36 * 64]; // 18432 B
  __shared__ float lds_sx[5 * 144];          // shape rows, edge-clamped
  __shared__ float qred[4][64];

  unsigned short* A0 = (unsigned short*)arena;
  float* lds_c = (float*)arena;

  const int tid = threadIdx.x;
  const int blk = blockIdx.x;
  const int coh = blk & 1;
  const int rp  = (blk >> 1) & 15;
  const int b   = blk >> 5;
  const int r0  = rp * 2;

  const int w    = tid >> 6;
  const int lane = tid & 63;
  const int rsel = w >> 1;          // MFMA-phase: wave's row within pair
  const int cq   = w & 1;           // MFMA-phase: co quarter within half
  const int n16  = lane & 15;
  const int kq   = lane >> 4;

  const float* xb = xg + (size_t)b * CX * LPIX;
  const float* xs = xb + CI * LPIX;

  // ---- stage B: x rows r0-1..r0+2, col slot s holds global col s-1, bf16,
  // ci-group XOR-swizzled by (slot&7). Zero rows/cols OOB.
  {
    const int col = tid & 31;          // global col = lane32
    const int grp = tid >> 5;          // 8 groups
    const int slot = col + 1;
    const int swk = (slot & 7) << 3;
    #pragma unroll
    for (int it = 0; it < 16; ++it) {
      const int rc  = grp + it * 8;    // 0..127 = row(2b) x cipair(5b)
      const int row = rc >> 5;
      const int ci  = (rc & 31) * 2;
      const int grow = r0 - 1 + row;
      unsigned v = 0;
      if ((unsigned)grow < 32u) {
        float f0 = xb[ci * LPIX + grow * 32 + col];
        float f1 = xb[(ci + 1) * LPIX + grow * 32 + col];
        v = (unsigned)f2bf(f0) | ((unsigned)f2bf(f1) << 16);
      }
      const int gslot = ((ci >> 3) << 3) ^ swk;
      ((unsigned*)ldsB)[(((row * 36 + slot) << 6) + gslot + (ci & 7)) >> 1] = v;
    }
    // zero pad slots 0,33,34,35 (4 rows x 32 ci-pairs each)
    for (int idx = tid; idx < 512; idx += 256) {
      const int row = idx >> 7;
      const int s4  = (idx >> 5) & 3;
      const int sl  = (s4 == 0) ? 0 : (32 + s4);
      const int ci  = (idx & 31) * 2;
      const int gsl = ((ci >> 3) << 3) ^ ((sl & 7) << 3);
      ((unsigned*)ldsB)[(((row * 36 + sl) << 6) + gsl + (ci & 7)) >> 1] = 0;
    }
  }

  // ---- stage shape rows (edge clamp) for the epilogue
  for (int idx = tid; idx < 5 * 144; idx += 256) {
    int c = idx / 144, rem = idx - c * 144;
    int s = rem / 36, j = rem - s * 36;
    int hh = r0 - 1 + s; hh = hh < 0 ? 0 : (hh > 31 ? 31 : hh);
    int col = j - 1;     col = col < 0 ? 0 : (col > 31 ? 31 : col);
    lds_sx[idx] = xs[c * LPIX + hh * 32 + col];
  }

  // ---- stage tap 0 A-tile (this co half: 64 co x 64 ci bf16 = 8 KB)
  {
    const uint4* s = (const uint4*)(wmf + (size_t)(coh * 64) * 64);
    uint4 v0 = s[tid], v1 = s[tid + 256];
    uint4* d = (uint4*)A0;
    d[tid] = v0; d[tid + 256] = v1;
  }
  __syncthreads();

  f32x4 acc[2][2] = {};

  for (int tap = 0; tap < 9; ++tap) {
    const int dr = tap / 3, dc = tap % 3;
    uint4 pf0, pf1;
    if (tap < 8) {
      const uint4* s = (const uint4*)(wmf + (size_t)((tap + 1) * 128 + coh * 64) * 64);
      pf0 = s[tid]; pf1 = s[tid + 256];
    }
    const int rowst = rsel + dr;                 // staged row 0..3
    const unsigned short* abase = A0 + (tap & 1) * 4096;
    #pragma unroll
    for (int ci0 = 0; ci0 < 64; ci0 += 32) {
      const int g = (ci0 >> 3) + kq;             // ci group 0..7
      bf16x8 bfr[2];
      #pragma unroll
      for (int t = 0; t < 2; ++t) {
        const int slot = t * 16 + n16 + dc;      // 0..33
        const int gs = (g ^ (slot & 7)) << 3;
        bfr[t] = *(const bf16x8*)(ldsB + ((rowst * 36 + slot) << 6) + gs);
      }
      const int gsa = ((kq | (ci0 >> 3)) ^ (n16 & 7)) << 3;
      #pragma unroll
      for (int ct = 0; ct < 2; ++ct) {
        const int co_l = cq * 32 + ct * 16 + n16;
        bf16x8 a = *(const bf16x8*)(abase + co_l * 64 + gsa);
        acc[0][ct] = __builtin_amdgcn_mfma_f32_16x16x32_bf16(a, bfr[0], acc[0][ct], 0, 0, 0);
        acc[1][ct] = __builtin_amdgcn_mfma_f32_16x16x32_bf16(a, bfr[1], acc[1][ct], 0, 0, 0);
      }
    }
    if (tap < 8) {
      uint4* d = (uint4*)(A0 + ((tap + 1) & 1) * 4096);
      d[tid] = pf0; d[tid + 256] = pf1;
    }
    __syncthreads();   // also separates last A-reads from lds_c writes below
  }

  // ---- transpose acc through LDS: [px 0..63][co_l 0..63], XOR-swizzled f32x4
  // C layout (validated r5/r6): col(px in tile)=n16, row(co in tile)=kq*4+reg
  #pragma unroll
  for (int pt = 0; pt < 2; ++pt) {
    const int pxl = rsel * 32 + pt * 16 + n16;
    #pragma unroll
    for (int ct = 0; ct < 2; ++ct) {
      const int cog = cq * 8 + ct * 4 + kq;       // co_l/4 group: 0..15
      const int sg  = cog ^ (pxl & 7);
      *(f32x4*)&lds_c[pxl * 64 + sg * 4] = acc[pt][ct];
    }
  }
  __syncthreads();

  // ---- epilogue: wave wS -> co chunk [wS*16, wS*16+16) of this half; lane = px
  const int wS   = __builtin_amdgcn_readfirstlane(w);
  const int co0g = coh * 64 + wS * 16;
  const int pxl  = lane;

  float cvals[16];
  #pragma unroll
  for (int g = 0; g < 4; ++g) {
    const int cog = wS * 4 + g;
    const int sg  = cog ^ (pxl & 7);
    *(f32x4*)&cvals[g * 4] = *(const f32x4*)&lds_c[pxl * 64 + sg * 4];
  }

  // shape windows into registers (center-relative for channels 0,1)
  const int xbase = (pxl >> 5) * 36 + (pxl & 31);
  float swv[45];
  {
    const float c0 = lds_sx[0 * 144 + 37 + xbase];
    const float c1 = lds_sx[1 * 144 + 37 + xbase];
    #pragma unroll
    for (int c = 0; c < 5; ++c) {
      float ctr = (c == 0) ? c0 : ((c == 1) ? c1 : 0.f);
      #pragma unroll
      for (int s = 0; s < 3; ++s)
        #pragma unroll
        for (int dc = 0; dc < 3; ++dc)
          swv[c * 9 + s * 3 + dc] = lds_sx[c * 144 + s * 36 + dc + xbase] - ctr;
    }
  }

  // sd via wave-uniform scalar loads + pure VALU
  float sd[16];
  #pragma unroll
  for (int k = 0; k < 16; ++k) sd[k] = 0.f;
  const float* skt = sktg + co0g;
  #pragma unroll
  for (int j = 0; j < 45; ++j) {
    const float sv = swv[j];
    #pragma unroll
    for (int k = 0; k < 16; ++k)
      sd[k] += fabsf(sv - skt[j * 128 + k]);
  }

  // bias + saf = relu(conv/(sd+1)) + store + q partial
  float qpv = 0.f;
  float* ob = outg + ((size_t)b * 133 + co0g) * LPIX + (r0 + (pxl >> 5)) * 32 + (pxl & 31);
  #pragma unroll
  for (int k = 0; k < 16; ++k) {
    float v = (cvals[k] + cbg[co0g + k]) * __builtin_amdgcn_rcpf(sd[k] + 1.0f);
    v = v > 0.f ? v : 0.f;
    ob[(size_t)k * LPIX] = v;
    qpv = fmaf(v, w2g[co0g + k], qpv);
  }

  // in-block q reduction over the 4 waves (this half's 64 co)
  qred[w][lane] = qpv;
  __syncthreads();
  if (tid < 64) {
    float q = qred[0][tid] + qred[1][tid] + qred[2][tid] + qred[3][tid];
    qp[coh * 16384 + b * LPIX + r0 * 32 + tid] = q;
  }
}

// ---------------------------------------------------------------------------
// statsB: combine q halves, 3x3 zero-padded softmax + weighted window stats
// ---------------------------------------------------------------------------
__launch_bounds__(64)
__global__ void statsB(const float* __restrict__ xg,
                       const float* __restrict__ qp,
                       const float* __restrict__ b2g,
                       float* __restrict__ outg) {
  const int gid = blockIdx.x * 64 + threadIdx.x;  // 0..16383
  const int b = gid >> 10;
  const int h = (gid >> 5) & 31;
  const int w = gid & 31;

  const float b2 = b2g[0];
  const float* q0 = qp + (size_t)b * LPIX;
  float qv[9];
  float m = -1e30f;
  #pragma unroll
  for (int t = 0; t < 9; ++t) {
    int hh = h + t / 3 - 1, wc = w + t % 3 - 1;
    float v = 0.f;  // zero padding participates in softmax
    if ((unsigned)hh < 32u && (unsigned)wc < 32u) {
      int off = hh * 32 + wc;
      v = (q0[off] + q0[16384 + off] + b2) * 0.08838834764831845f;  // 1/sqrt(128)
    }
    qv[t] = v;
    m = fmaxf(m, v);
  }
  float ssum = 0.f;
  #pragma unroll
  for (int t = 0; t < 9; ++t) { qv[t] = expf(qv[t] - m); ssum += qv[t]; }
  const float inv = 1.f / ssum;

  const float* xs = xg + ((size_t)b * CX + CI) * LPIX;
  float um0[9], um1[9];
  float m0 = 0.f, m1 = 0.f, v1a = 0.f, v1b = 0.f, c1 = 0.f;
  #pragma unroll
  for (int t = 0; t < 9; ++t) {
    int hh = h + t / 3 - 1; hh = hh < 0 ? 0 : (hh > 31 ? 31 : hh);  // edge pad
    int wc = w + t % 3 - 1; wc = wc < 0 ? 0 : (wc > 31 ? 31 : wc);
    int off = hh * 32 + wc;
    float quv = qv[t] * inv;
    qv[t] = quv;
    float a0 = xs[off];
    float a1 = xs[LPIX + off];
    float b0 = xs[2 * LPIX + off];
    float b1 = xs[3 * LPIX + off];
    float cc = xs[4 * LPIX + off];
    um0[t] = a0; um1[t] = a1;
    m0 = fmaf(a0, quv, m0);
    m1 = fmaf(a1, quv, m1);
    v1a = fmaf(b0, quv, v1a);
    v1b = fmaf(b1, quv, v1b);
    c1 = fmaf(cc, quv, c1);
  }
  float var0 = v1a, var1 = v1b, cov = c1;
  #pragma unroll
  for (int t = 0; t < 9; ++t) {
    float d0 = um0[t] - m0, d1 = um1[t] - m1;
    var0 = fmaf(d0 * d0, qv[t], var0);
    var1 = fmaf(d1 * d1, qv[t], var1);
    cov  = fmaf(d0 * d1, qv[t], cov);
  }
  float* ob = outg + ((size_t)b * 133 + 128) * LPIX + h * 32 + w;
  ob[0 * LPIX] = m0;
  ob[1 * LPIX] = m1;
  ob[2 * LPIX] = var0;
  ob[3 * LPIX] = var1;
  ob[4 * LPIX] = cov;
}

extern "C" void kernel_launch(void* const* d_in, const int* in_sizes, int n_in,
                              void* d_out, int out_size, void* d_ws, size_t ws_size,
                              hipStream_t stream) {
  const float* x  = (const float*)d_in[0];
  const float* cw = (const float*)d_in[1];
  const float* cb = (const float*)d_in[2];
  const float* w2 = (const float*)d_in[3];
  const float* b2 = (const float*)d_in[4];
  const float* sk = (const float*)d_in[5];
  float* out = (float*)d_out;

  unsigned short* wmf = (unsigned short*)((char*)d_ws + WMF_OFF);
  float* skt = (float*)((char*)d_ws + SKT_OFF);
  float* qp  = (float*)((char*)d_ws + QP_OFF);

  prepW<<<dim3(311), dim3(256), 0, stream>>>(cw, sk, wmf, skt);
  convFused<<<dim3(512), dim3(256), 0, stream>>>(x, wmf, cb, w2, skt, qp, out);
  statsB<<<dim3(256), dim3(64), 0, stream>>>(x, qp, b2, out);
}